// Round 1
// baseline (667.100 us; speedup 1.0000x reference)
//
#include <hip/hip_runtime.h>
#include <hip/hip_bf16.h>

#define DEVI __device__ __forceinline__

static constexpr int cB = 4, cC = 64, cH = 384, cW = 384;
static constexpr int cHW = cH * cW;           // 147456
static constexpr int cP  = 2048;              // MAX_POS
static constexpr int cKC = 20480;             // candidate pool
static constexpr int cKN = 10240;             // max negatives
static constexpr int cNT = cP + cKN;          // 12288 rows of G = [pf; nf]
static constexpr float cTEMP_INV = 10.0f;     // 1/TEMP

using f32x4  = __attribute__((ext_vector_type(4))) float;
using bf16x8 = __attribute__((ext_vector_type(8))) __bf16;

// ---- workspace layout (bytes, all 256-aligned) ----
static constexpr size_t off_fg   = 0;
static constexpr size_t off_tmp  = off_fg   + (size_t)cB * cHW;          // 589824
static constexpr size_t off_rim  = off_tmp  + (size_t)cB * cHW;
static constexpr size_t off_pidx = off_rim  + (size_t)cB * cHW;          // 1769472
static constexpr size_t off_cidx = off_pidx + (size_t)cB * cP * 4;
static constexpr size_t off_scal = off_cidx + (size_t)cB * cKC * 4;
static constexpr size_t off_loss = off_scal + (size_t)cB * 16 * 4;
static constexpr size_t off_msim = off_loss + 256;
static constexpr size_t off_nsel = off_msim + (size_t)cB * cKC * 4;
static constexpr size_t off_G    = off_nsel + (size_t)cB * cKN * 4;      // 2621952
static constexpr size_t off_cf   = off_G    + (size_t)cB * cNT * cC * 2; // +6.29MB
// total ≈ 19.4 MB

// ---------------- masks ----------------
__global__ void k_fg(const int* labels, unsigned char* fg) {
  int i = blockIdx.x * 256 + threadIdx.x;
  if (i < cB * cHW) fg[i] = labels[i] > 0;
}

__global__ void k_hdil(const unsigned char* fg, unsigned char* tmp) {
  int i = blockIdx.x * 256 + threadIdx.x;
  if (i >= cB * cHW) return;
  int x = i % cW;
  int rowbase = i - x;
  int lo = max(x - 5, 0), hi = min(x + 5, cW - 1);
  unsigned char m = 0;
  for (int xx = lo; xx <= hi; xx++) m |= fg[rowbase + xx];
  tmp[i] = m;
}

__global__ void k_vdil(const unsigned char* tmp, const unsigned char* fg, unsigned char* rim) {
  int i = blockIdx.x * 256 + threadIdx.x;
  if (i >= cB * cHW) return;
  int b = i / cHW, p = i % cHW;
  int y = p / cW, x = p % cW;
  int lo = max(y - 5, 0), hi = min(y + 5, cH - 1);
  unsigned char m = 0;
  const unsigned char* base = tmp + (size_t)b * cHW;
  for (int yy = lo; yy <= hi; yy++) m |= base[yy * cW + x];
  rim[i] = m & (fg[i] ^ 1);
}

// ---------------- ordered compaction helpers ----------------
__device__ int scan_excl_1024(int v, int* lds, int* total) {
  int tid = threadIdx.x;
  lds[tid] = v;
  __syncthreads();
  for (int d = 1; d < 1024; d <<= 1) {
    int t = (tid >= d) ? lds[tid - d] : 0;
    __syncthreads();
    lds[tid] += t;
    __syncthreads();
  }
  *total = lds[1023];
  int e = lds[tid] - v;
  __syncthreads();
  return e;
}

// one block per image: raster-order compaction of fg->pidx (fill !fg), rim->cidx (fill !rim)
__global__ __launch_bounds__(1024) void k_select(const unsigned char* fg, const unsigned char* rim,
                                                 int* pidx, int* cidx, int* scal) {
  __shared__ int lds[1024];
  int b = blockIdx.x, tid = threadIdx.x;
  const unsigned char* fgb  = fg  + (size_t)b * cHW;
  const unsigned char* rimb = rim + (size_t)b * cHW;
  int* pout = pidx + (size_t)b * cP;
  int* cout = cidx + (size_t)b * cKC;
  const int CH = cHW / 1024;  // 144
  int s = tid * CH;
  int total, off, o, cnt;

  cnt = 0;
  for (int e = 0; e < CH; e++) cnt += fgb[s + e];
  off = scan_excl_1024(cnt, lds, &total);
  o = off;
  for (int e = 0; e < CH; e++) if (fgb[s + e]) { if (o < cP) pout[o] = s + e; o++; }
  int nfg = total;
  if (nfg < cP) {
    cnt = 0;
    for (int e = 0; e < CH; e++) cnt += fgb[s + e] ^ 1;
    off = scan_excl_1024(cnt, lds, &total);
    o = nfg + off;
    for (int e = 0; e < CH; e++) if (!fgb[s + e]) { if (o >= 0 && o < cP) pout[o] = s + e; o++; }
  }

  cnt = 0;
  for (int e = 0; e < CH; e++) cnt += rimb[s + e];
  off = scan_excl_1024(cnt, lds, &total);
  o = off;
  for (int e = 0; e < CH; e++) if (rimb[s + e]) { if (o < cKC) cout[o] = s + e; o++; }
  int nrim = total;
  if (nrim < cKC) {
    cnt = 0;
    for (int e = 0; e < CH; e++) cnt += rimb[s + e] ^ 1;
    off = scan_excl_1024(cnt, lds, &total);
    o = nrim + off;
    for (int e = 0; e < CH; e++) if (!rimb[s + e]) { if (o >= 0 && o < cKC) cout[o] = s + e; o++; }
  }
  if (tid == 0) {
    scal[b * 16 + 0] = nfg;
    scal[b * 16 + 1] = min(nfg, cP);    // P_valid
    scal[b * 16 + 2] = min(nrim, cKC);  // C_valid
  }
}

// ---------------- gather + L2-normalize -> bf16 rows ----------------
__global__ __launch_bounds__(256) void k_gather_norm(const float* feat, const int* idxs, int idx_stride,
                                                     int count, __hip_bfloat16* dst, size_t dst_img_stride) {
  int b = blockIdx.y;
  int i = blockIdx.x * 256 + threadIdx.x;
  if (i >= count) return;
  int p = idxs[(size_t)b * idx_stride + i];
  const float* fb = feat + (size_t)b * cC * cHW + p;
  float v[cC];
  float ss = 0.f;
#pragma unroll
  for (int c = 0; c < cC; c++) { float t = fb[(size_t)c * cHW]; v[c] = t; ss += t * t; }
  float sc = 1.0f / fmaxf(sqrtf(ss), 1e-8f);
  __hip_bfloat16* out = dst + (size_t)b * dst_img_stride + (size_t)i * cC;
#pragma unroll
  for (int c = 0; c < cC; c++) out[c] = __float2bfloat16(v[c] * sc);
}

// ---------------- hard-negative mining: column max of pf @ cf^T ----------------
__global__ __launch_bounds__(256) void k_mine(const __hip_bfloat16* G, const __hip_bfloat16* cf,
                                              const int* scal, float* msim) {
  int b = blockIdx.y;
  int P_valid = scal[b * 16 + 1];
  int wave = threadIdx.x >> 6, lane = threadIdx.x & 63;
  int lr = lane & 15, quad = lane >> 4;
  int colbase = blockIdx.x * 128 + wave * 32;
  const __bf16* pf  = (const __bf16*)(G  + (size_t)b * cNT * cC);
  const __bf16* cfb = (const __bf16*)(cf + (size_t)b * cKC * cC);

  bf16x8 bfr[2][2];
#pragma unroll
  for (int t = 0; t < 2; t++) {
    const __bf16* src = cfb + (size_t)(colbase + t * 16 + lr) * cC + quad * 8;
    bfr[t][0] = *(const bf16x8*)src;
    bfr[t][1] = *(const bf16x8*)(src + 32);
  }
  float cmax0 = -INFINITY, cmax1 = -INFINITY;
  for (int mt = 0; mt < cP / 16; mt++) {
    const __bf16* asrc = pf + (size_t)(mt * 16 + lr) * cC + quad * 8;
    bf16x8 a0 = *(const bf16x8*)asrc;
    bf16x8 a1 = *(const bf16x8*)(asrc + 32);
    f32x4 acc0 = {0, 0, 0, 0}, acc1 = {0, 0, 0, 0};
    acc0 = __builtin_amdgcn_mfma_f32_16x16x32_bf16(a0, bfr[0][0], acc0, 0, 0, 0);
    acc0 = __builtin_amdgcn_mfma_f32_16x16x32_bf16(a1, bfr[0][1], acc0, 0, 0, 0);
    acc1 = __builtin_amdgcn_mfma_f32_16x16x32_bf16(a0, bfr[1][0], acc1, 0, 0, 0);
    acc1 = __builtin_amdgcn_mfma_f32_16x16x32_bf16(a1, bfr[1][1], acc1, 0, 0, 0);
    int rb = mt * 16 + quad * 4;
#pragma unroll
    for (int r = 0; r < 4; r++) {
      bool rv = (rb + r) < P_valid;
      cmax0 = fmaxf(cmax0, rv ? acc0[r] : -INFINITY);
      cmax1 = fmaxf(cmax1, rv ? acc1[r] : -INFINITY);
    }
  }
  cmax0 = fmaxf(cmax0, __shfl_xor(cmax0, 16));
  cmax0 = fmaxf(cmax0, __shfl_xor(cmax0, 32));
  cmax1 = fmaxf(cmax1, __shfl_xor(cmax1, 16));
  cmax1 = fmaxf(cmax1, __shfl_xor(cmax1, 32));
  if (quad == 0) {
    msim[(size_t)b * cKC + colbase + lr]      = cmax0;
    msim[(size_t)b * cKC + colbase + 16 + lr] = cmax1;
  }
}

// ---------------- top-KEEP selection (radix threshold; set semantics) ----------------
DEVI unsigned f2key(float f) {
  unsigned u = __float_as_uint(f);
  return (u & 0x80000000u) ? ~u : (u | 0x80000000u);
}

__global__ __launch_bounds__(1024) void k_selneg(const float* msim, int* nsel, int* scal) {
  __shared__ int hist[256];
  __shared__ int lds[1024];
  __shared__ unsigned sh_prefix;
  __shared__ int sh_rem;
  int b = blockIdx.x, tid = threadIdx.x;
  const float* ms = msim + (size_t)b * cKC;
  int P_valid = scal[b * 16 + 1], C_valid = scal[b * 16 + 2];
  int n_allowed = min(5 * P_valid, cKN);
  int nfin = (P_valid > 0) ? C_valid : 0;   // valid candidates have finite max_sim iff >=1 valid positive
  int KEEP = min(n_allowed, nfin);
  if (tid == 0) scal[b * 16 + 3] = KEEP;
  if (KEEP == 0) return;  // uniform

  unsigned prefix = 0;
  int remaining = KEEP;
  for (int shift = 24; shift >= 0; shift -= 8) {
    if (tid < 256) hist[tid] = 0;
    __syncthreads();
    for (int c = tid; c < cKC; c += 1024) {
      unsigned key = (c < C_valid) ? f2key(ms[c]) : 0u;
      if (shift == 24 || (key >> (shift + 8)) == prefix)
        atomicAdd(&hist[(key >> shift) & 255], 1);
    }
    __syncthreads();
    if (tid == 0) {
      int rem = remaining, bsel = 0;
      for (int bin = 255; bin >= 0; bin--) {
        int h = hist[bin];
        if (h >= rem) { bsel = bin; break; }
        rem -= h;
      }
      sh_prefix = (prefix << 8) | (unsigned)bsel;
      sh_rem = rem;
    }
    __syncthreads();
    prefix = sh_prefix; remaining = sh_rem;
    __syncthreads();
  }
  unsigned T = prefix;       // KEEP-th largest key; remaining = #ties to take

  const int CH2 = cKC / 1024;  // 20
  int s = tid * CH2;
  unsigned keys[CH2];
  int cntA = 0, cntT = 0;
  for (int e = 0; e < CH2; e++) {
    int c = s + e;
    unsigned key = (c < C_valid) ? f2key(ms[c]) : 0u;
    keys[e] = key;
    cntA += (key > T);
    cntT += (key == T);
  }
  int totA, totT;
  int offA = scan_excl_1024(cntA, lds, &totA);
  int offT = scan_excl_1024(cntT, lds, &totT);
  int* out = nsel + (size_t)b * cKN;
  int oa = offA, ot = offT;
  for (int e = 0; e < CH2; e++) {
    unsigned key = keys[e];
    if (key > T) { out[oa++] = s + e; }
    else if (key == T) { if (ot < remaining) out[totA + ot] = s + e; ot++; }
  }
}

// ---------------- gather negatives into G (zero unused rows) ----------------
__global__ __launch_bounds__(256) void k_gather_neg(const __hip_bfloat16* cf, const int* nsel,
                                                    const int* scal, __hip_bfloat16* G) {
  int b = blockIdx.y;
  int KEEP = scal[b * 16 + 3];
  int t = blockIdx.x * 256 + threadIdx.x;  // over cKN * 8 16B-chunks
  int k = t >> 3, part = t & 7;
  if (k >= cKN) return;
  int4 val = {0, 0, 0, 0};
  if (k < KEEP) {
    int src = nsel[(size_t)b * cKN + k];
    val = *(const int4*)((const __bf16*)(cf + (size_t)b * cKC * cC) + (size_t)src * cC + part * 8);
  }
  *(int4*)((__bf16*)(G + (size_t)b * cNT * cC) + (size_t)(cP + k) * cC + part * 8) = val;
}

// ---------------- fused loss GEMM: logits = 10 * (pf @ G^T), row logsumexp + lpp sum ----------------
__global__ __launch_bounds__(256) void k_loss(const __hip_bfloat16* G, const int* scal, float* loss_sum) {
  __shared__ float sE[4][32];
  __shared__ float sL[4][32];
  int b = blockIdx.y;
  int P_valid = scal[b * 16 + 1];
  int KEEP = scal[b * 16 + 3];
  if (P_valid < 2) return;  // image contributes nothing (has=false)
  int wave = threadIdx.x >> 6, lane = threadIdx.x & 63;
  int lr = lane & 15, quad = lane >> 4;
  int rowbase = blockIdx.x * 32;
  const __bf16* Gb = (const __bf16*)G + (size_t)b * cNT * cC;

  bf16x8 afr[2][2];
#pragma unroll
  for (int rt = 0; rt < 2; rt++) {
    const __bf16* src = Gb + (size_t)(rowbase + rt * 16 + lr) * cC + quad * 8;
    afr[rt][0] = *(const bf16x8*)src;
    afr[rt][1] = *(const bf16x8*)(src + 32);
  }
  float eacc[2][4] = {{0, 0, 0, 0}, {0, 0, 0, 0}};
  float lacc[2][4] = {{0, 0, 0, 0}, {0, 0, 0, 0}};
  for (int ct = wave; ct < cNT / 16; ct += 4) {
    int col = ct * 16 + lr;  // global G row of this B-column
    const __bf16* bsrc = Gb + (size_t)col * cC + quad * 8;
    bf16x8 b0 = *(const bf16x8*)bsrc;
    bf16x8 b1 = *(const bf16x8*)(bsrc + 32);
    bool is_pos = col < cP;
    bool vcol = is_pos ? (col < P_valid) : ((col - cP) < KEEP);
#pragma unroll
    for (int rt = 0; rt < 2; rt++) {
      f32x4 acc = {0, 0, 0, 0};
      acc = __builtin_amdgcn_mfma_f32_16x16x32_bf16(afr[rt][0], b0, acc, 0, 0, 0);
      acc = __builtin_amdgcn_mfma_f32_16x16x32_bf16(afr[rt][1], b1, acc, 0, 0, 0);
      int rb = rowbase + rt * 16 + quad * 4;
#pragma unroll
      for (int r = 0; r < 4; r++) {
        float logit = acc[r] * cTEMP_INV;
        bool use = vcol && !(is_pos && (col == rb + r));  // exclude diagonal
        float e = __expf(logit);
        eacc[rt][r] += use ? e : 0.0f;
        lacc[rt][r] += (use && is_pos) ? logit : 0.0f;
      }
    }
  }
#pragma unroll
  for (int rt = 0; rt < 2; rt++) {
#pragma unroll
    for (int r = 0; r < 4; r++) {
      float e = eacc[rt][r], l = lacc[rt][r];
#pragma unroll
      for (int d = 1; d < 16; d <<= 1) {
        e += __shfl_xor(e, d);
        l += __shfl_xor(l, d);
      }
      if (lr == 0) {
        sE[wave][rt * 16 + quad * 4 + r] = e;
        sL[wave][rt * 16 + quad * 4 + r] = l;
      }
    }
  }
  __syncthreads();
  if (threadIdx.x < 32) {
    int row = rowbase + threadIdx.x;
    float E = sE[0][threadIdx.x] + sE[1][threadIdx.x] + sE[2][threadIdx.x] + sE[3][threadIdx.x];
    float L = sL[0][threadIdx.x] + sL[1][threadIdx.x] + sL[2][threadIdx.x] + sL[3][threadIdx.x];
    if (row < P_valid) {
      float li = logf(E) - L / (float)(P_valid - 1);
      atomicAdd(&loss_sum[b], li);
    }
  }
}

__global__ void k_init(float* loss_sum) {
  int t = threadIdx.x;
  if (t < cB) loss_sum[t] = 0.0f;
}

__global__ void k_final(const int* scal, const float* loss_sum, float* out) {
  float tot = 0.f;
  int cnt = 0;
  for (int b = 0; b < cB; b++) {
    int Pv = scal[b * 16 + 1];
    if (Pv >= 2) { tot += loss_sum[b] / (float)Pv; cnt++; }
  }
  out[0] = tot / (float)((cnt > 0) ? cnt : 1);
}

extern "C" void kernel_launch(void* const* d_in, const int* in_sizes, int n_in,
                              void* d_out, int out_size, void* d_ws, size_t ws_size,
                              hipStream_t stream) {
  const float* feat = (const float*)d_in[0];
  const int* labels = (const int*)d_in[1];
  char* ws = (char*)d_ws;
  unsigned char* fg  = (unsigned char*)(ws + off_fg);
  unsigned char* tmp = (unsigned char*)(ws + off_tmp);
  unsigned char* rim = (unsigned char*)(ws + off_rim);
  int* pidx = (int*)(ws + off_pidx);
  int* cidx = (int*)(ws + off_cidx);
  int* scal = (int*)(ws + off_scal);
  float* loss_sum = (float*)(ws + off_loss);
  float* msim = (float*)(ws + off_msim);
  int* nsel = (int*)(ws + off_nsel);
  __hip_bfloat16* G  = (__hip_bfloat16*)(ws + off_G);
  __hip_bfloat16* cf = (__hip_bfloat16*)(ws + off_cf);
  float* out = (float*)d_out;

  int nElem = cB * cHW;
  k_init<<<1, 64, 0, stream>>>(loss_sum);
  k_fg<<<(nElem + 255) / 256, 256, 0, stream>>>(labels, fg);
  k_hdil<<<(nElem + 255) / 256, 256, 0, stream>>>(fg, tmp);
  k_vdil<<<(nElem + 255) / 256, 256, 0, stream>>>(tmp, fg, rim);
  k_select<<<cB, 1024, 0, stream>>>(fg, rim, pidx, cidx, scal);
  k_gather_norm<<<dim3(cP / 256, cB), 256, 0, stream>>>(feat, pidx, cP, cP, G, (size_t)cNT * cC);
  k_gather_norm<<<dim3(cKC / 256, cB), 256, 0, stream>>>(feat, cidx, cKC, cKC, cf, (size_t)cKC * cC);
  k_mine<<<dim3(cKC / 128, cB), 256, 0, stream>>>(G, cf, scal, msim);
  k_selneg<<<cB, 1024, 0, stream>>>(msim, nsel, scal);
  k_gather_neg<<<dim3(cKN * 8 / 256, cB), 256, 0, stream>>>(cf, nsel, scal, G);
  k_loss<<<dim3(cP / 32, cB), 256, 0, stream>>>(G, scal, loss_sum);
  k_final<<<1, 1, 0, stream>>>(scal, loss_sum, out);
}

// Round 2
// 477.902 us; speedup vs baseline: 1.3959x; 1.3959x over previous
//
#include <hip/hip_runtime.h>
#include <hip/hip_bf16.h>

#define DEVI __device__ __forceinline__

static constexpr int cB = 4, cC = 64, cH = 384, cW = 384;
static constexpr int cHW = cH * cW;           // 147456
static constexpr int cP  = 2048;              // MAX_POS
static constexpr int cKC = 20480;             // candidate pool
static constexpr int cKN = 10240;             // max negatives
static constexpr int cNT = cP + cKN;          // 12288 rows of G = [pf; nf]
static constexpr float cTEMP_INV = 10.0f;     // 1/TEMP
static constexpr int cCHUNK = 2048;           // elems per selection block
static constexpr int cNB = cHW / cCHUNK;      // 72 selection blocks per image

using f32x4  = __attribute__((ext_vector_type(4))) float;
using bf16x8 = __attribute__((ext_vector_type(8))) __bf16;

// ---- workspace layout (bytes) ----
static constexpr size_t off_fg   = 0;
static constexpr size_t off_tmp  = off_fg   + (size_t)cB * cHW;
static constexpr size_t off_rim  = off_tmp  + (size_t)cB * cHW;
static constexpr size_t off_pidx = off_rim  + (size_t)cB * cHW;
static constexpr size_t off_cidx = off_pidx + (size_t)cB * cP * 4;
static constexpr size_t off_scal = off_cidx + (size_t)cB * cKC * 4;
static constexpr size_t off_loss = off_scal + (size_t)cB * 16 * 4;
static constexpr size_t off_msim = off_loss + 256;
static constexpr size_t off_nsel = off_msim + (size_t)cB * cKC * 4;
static constexpr size_t off_G    = off_nsel + (size_t)cB * cKN * 4;
static constexpr size_t off_cf   = off_G    + (size_t)cB * cNT * cC * 2;
static constexpr size_t off_bcnt = off_cf   + (size_t)cB * cKC * cC * 2;  // 19399168
static constexpr size_t off_boff = off_bcnt + (size_t)cB * cNB * 4;
// total ≈ 19.41 MB

// ---------------- masks ----------------
__global__ void k_fg(const int* labels, unsigned char* fg) {
  int i = blockIdx.x * 256 + threadIdx.x;
  if (i < cB * cHW) fg[i] = labels[i] > 0;
}

__global__ void k_hdil(const unsigned char* fg, unsigned char* tmp) {
  int i = blockIdx.x * 256 + threadIdx.x;
  if (i >= cB * cHW) return;
  int x = i % cW;
  int rowbase = i - x;
  int lo = max(x - 5, 0), hi = min(x + 5, cW - 1);
  unsigned char m = 0;
  for (int xx = lo; xx <= hi; xx++) m |= fg[rowbase + xx];
  tmp[i] = m;
}

// vertical dilation + rim + per-block packed counts (fg | rim<<16)
__global__ __launch_bounds__(256) void k_vdil_count(const unsigned char* tmp, const unsigned char* fg,
                                                    unsigned char* rim, int* blkcnt) {
  __shared__ int red[256];
  int b = blockIdx.y, blk = blockIdx.x, tid = threadIdx.x;
  int base = blk * cCHUNK + tid * 8;
  const unsigned char* tb  = tmp + (size_t)b * cHW;
  const unsigned char* fgb = fg  + (size_t)b * cHW;
  unsigned long long fv = *(const unsigned long long*)(fgb + base);
  unsigned long long pk = 0;
  int crim = 0;
#pragma unroll
  for (int e = 0; e < 8; e++) {
    int p = base + e;
    int y = p / cW, x = p - y * cW;
    int lo = max(y - 5, 0), hi = min(y + 5, cH - 1);
    unsigned char m = 0;
    for (int yy = lo; yy <= hi; yy++) m |= tb[yy * cW + x];
    unsigned char f = (unsigned char)((fv >> (8 * e)) & 1);
    unsigned char rv = m & (f ^ 1);
    pk |= (unsigned long long)rv << (8 * e);
    crim += rv;
  }
  *(unsigned long long*)(rim + (size_t)b * cHW + base) = pk;
  int cfg = __popcll(fv & 0x0101010101010101ULL);
  red[tid] = cfg | (crim << 16);
  __syncthreads();
  for (int s = 128; s > 0; s >>= 1) {
    if (tid < s) red[tid] += red[tid + s];
    __syncthreads();
  }
  if (tid == 0) blkcnt[b * cNB + blk] = red[0];
}

// per-image exclusive scan over the 72 block counts
__global__ __launch_bounds__(128) void k_offsets(const int* blkcnt, int2* blkoff, int* scal) {
  __shared__ int sf[128], sr[128];
  int b = blockIdx.x, tid = threadIdx.x;
  int v = (tid < cNB) ? blkcnt[b * cNB + tid] : 0;
  int f = v & 0xffff, r = v >> 16;
  sf[tid] = f; sr[tid] = r;
  __syncthreads();
  for (int d = 1; d < 128; d <<= 1) {
    int tf = (tid >= d) ? sf[tid - d] : 0;
    int tr = (tid >= d) ? sr[tid - d] : 0;
    __syncthreads();
    sf[tid] += tf; sr[tid] += tr;
    __syncthreads();
  }
  if (tid < cNB) blkoff[b * cNB + tid] = make_int2(sf[tid] - f, sr[tid] - r);
  if (tid == 0) {
    int nfg = sf[cNB - 1], nrim = sr[cNB - 1];
    scal[b * 16 + 0] = nfg;
    scal[b * 16 + 1] = min(nfg, cP);    // P_valid
    scal[b * 16 + 2] = min(nrim, cKC);  // C_valid
    scal[b * 16 + 4] = nrim;
  }
}

__device__ int scan_excl_256(int v, int* lds) {
  int tid = threadIdx.x;
  lds[tid] = v;
  __syncthreads();
  for (int d = 1; d < 256; d <<= 1) {
    int t = (tid >= d) ? lds[tid - d] : 0;
    __syncthreads();
    lds[tid] += t;
    __syncthreads();
  }
  int e = lds[tid] - v;
  __syncthreads();
  return e;
}

// raster-order scatter: fg->pidx (fill !fg), rim->cidx (fill !rim)
__global__ __launch_bounds__(256) void k_scatter(const unsigned char* fg, const unsigned char* rim,
                                                 const int2* blkoff, const int* scal,
                                                 int* pidx, int* cidx) {
  __shared__ int lds[256];
  int b = blockIdx.y, blk = blockIdx.x, tid = threadIdx.x;
  int2 off = blkoff[b * cNB + blk];
  int nfg  = scal[b * 16 + 0];
  int nrim = scal[b * 16 + 4];
  bool needf = (off.x < cP)  || (nfg  < cP);
  bool needr = (off.y < cKC) || (nrim < cKC);
  if (!needf && !needr) return;
  int base = blk * cCHUNK + tid * 8;
  const unsigned char* fgb  = fg  + (size_t)b * cHW;
  const unsigned char* rimb = rim + (size_t)b * cHW;
  unsigned long long fv = *(const unsigned long long*)(fgb + base);
  unsigned long long rv = *(const unsigned long long*)(rimb + base);
  int cfg  = __popcll(fv & 0x0101010101010101ULL);
  int crim = __popcll(rv & 0x0101010101010101ULL);
  int ex = scan_excl_256(cfg | (crim << 16), lds);
  int of  = off.x + (ex & 0xffff);
  int orr = off.y + (ex >> 16);
  int* pout = pidx + (size_t)b * cP;
  int* cout = cidx + (size_t)b * cKC;
#pragma unroll
  for (int e = 0; e < 8; e++) {
    int p = base + e;
    int f = (int)((fv >> (8 * e)) & 1);
    int r = (int)((rv >> (8 * e)) & 1);
    if (f) { if (of < cP) pout[of] = p; of++; }
    else if (nfg < cP) { int o = nfg + (p - of); if (o < cP) pout[o] = p; }
    if (r) { if (orr < cKC) cout[orr] = p; orr++; }
    else if (nrim < cKC) { int o = nrim + (p - orr); if (o < cKC) cout[o] = p; }
  }
}

// ---------------- gather + L2-normalize -> bf16 rows ----------------
__global__ __launch_bounds__(256) void k_gather_norm(const float* feat, const int* idxs, int idx_stride,
                                                     int count, __hip_bfloat16* dst, size_t dst_img_stride) {
  int b = blockIdx.y;
  int i = blockIdx.x * 256 + threadIdx.x;
  if (i >= count) return;
  int p = idxs[(size_t)b * idx_stride + i];
  const float* fb = feat + (size_t)b * cC * cHW + p;
  float v[cC];
  float ss = 0.f;
#pragma unroll
  for (int c = 0; c < cC; c++) { float t = fb[(size_t)c * cHW]; v[c] = t; ss += t * t; }
  float sc = 1.0f / fmaxf(sqrtf(ss), 1e-8f);
  __hip_bfloat16* out = dst + (size_t)b * dst_img_stride + (size_t)i * cC;
#pragma unroll
  for (int c = 0; c < cC; c++) out[c] = __float2bfloat16(v[c] * sc);
}

// ---------------- hard-negative mining: column max of pf @ cf^T ----------------
__global__ __launch_bounds__(256) void k_mine(const __hip_bfloat16* G, const __hip_bfloat16* cf,
                                              const int* scal, float* msim) {
  int b = blockIdx.y;
  int P_valid = scal[b * 16 + 1];
  int wave = threadIdx.x >> 6, lane = threadIdx.x & 63;
  int lr = lane & 15, quad = lane >> 4;
  int colbase = blockIdx.x * 128 + wave * 32;
  const __bf16* pf  = (const __bf16*)(G  + (size_t)b * cNT * cC);
  const __bf16* cfb = (const __bf16*)(cf + (size_t)b * cKC * cC);

  bf16x8 bfr[2][2];
#pragma unroll
  for (int t = 0; t < 2; t++) {
    const __bf16* src = cfb + (size_t)(colbase + t * 16 + lr) * cC + quad * 8;
    bfr[t][0] = *(const bf16x8*)src;
    bfr[t][1] = *(const bf16x8*)(src + 32);
  }
  float cmax0 = -INFINITY, cmax1 = -INFINITY;
  for (int mt = 0; mt < cP / 16; mt++) {
    const __bf16* asrc = pf + (size_t)(mt * 16 + lr) * cC + quad * 8;
    bf16x8 a0 = *(const bf16x8*)asrc;
    bf16x8 a1 = *(const bf16x8*)(asrc + 32);
    f32x4 acc0 = {0, 0, 0, 0}, acc1 = {0, 0, 0, 0};
    acc0 = __builtin_amdgcn_mfma_f32_16x16x32_bf16(a0, bfr[0][0], acc0, 0, 0, 0);
    acc0 = __builtin_amdgcn_mfma_f32_16x16x32_bf16(a1, bfr[0][1], acc0, 0, 0, 0);
    acc1 = __builtin_amdgcn_mfma_f32_16x16x32_bf16(a0, bfr[1][0], acc1, 0, 0, 0);
    acc1 = __builtin_amdgcn_mfma_f32_16x16x32_bf16(a1, bfr[1][1], acc1, 0, 0, 0);
    int rb = mt * 16 + quad * 4;
#pragma unroll
    for (int r = 0; r < 4; r++) {
      bool rv = (rb + r) < P_valid;
      cmax0 = fmaxf(cmax0, rv ? acc0[r] : -INFINITY);
      cmax1 = fmaxf(cmax1, rv ? acc1[r] : -INFINITY);
    }
  }
  cmax0 = fmaxf(cmax0, __shfl_xor(cmax0, 16));
  cmax0 = fmaxf(cmax0, __shfl_xor(cmax0, 32));
  cmax1 = fmaxf(cmax1, __shfl_xor(cmax1, 16));
  cmax1 = fmaxf(cmax1, __shfl_xor(cmax1, 32));
  if (quad == 0) {
    msim[(size_t)b * cKC + colbase + lr]      = cmax0;
    msim[(size_t)b * cKC + colbase + 16 + lr] = cmax1;
  }
}

// ---------------- top-KEEP selection (radix threshold; set semantics) ----------------
DEVI unsigned f2key(float f) {
  unsigned u = __float_as_uint(f);
  return (u & 0x80000000u) ? ~u : (u | 0x80000000u);
}

__device__ int scan_excl_1024(int v, int* lds, int* total) {
  int tid = threadIdx.x;
  lds[tid] = v;
  __syncthreads();
  for (int d = 1; d < 1024; d <<= 1) {
    int t = (tid >= d) ? lds[tid - d] : 0;
    __syncthreads();
    lds[tid] += t;
    __syncthreads();
  }
  *total = lds[1023];
  int e = lds[tid] - v;
  __syncthreads();
  return e;
}

__global__ __launch_bounds__(1024) void k_selneg(const float* msim, int* nsel, int* scal) {
  __shared__ int hist[256];
  __shared__ int suf[256];
  __shared__ int lds[1024];
  __shared__ unsigned sh_prefix;
  __shared__ int sh_rem;
  int b = blockIdx.x, tid = threadIdx.x;
  const float* ms = msim + (size_t)b * cKC;
  int P_valid = scal[b * 16 + 1], C_valid = scal[b * 16 + 2];
  int n_allowed = min(5 * P_valid, cKN);
  int nfin = (P_valid > 0) ? C_valid : 0;
  int KEEP = min(n_allowed, nfin);
  if (tid == 0) scal[b * 16 + 3] = KEEP;
  if (KEEP == 0) return;

  unsigned prefix = 0;
  int remaining = KEEP;
  for (int shift = 24; shift >= 0; shift -= 8) {
    if (tid < 256) hist[tid] = 0;
    __syncthreads();
    for (int c = tid; c < cKC; c += 1024) {
      unsigned key = (c < C_valid) ? f2key(ms[c]) : 0u;
      if (shift == 24 || (key >> (shift + 8)) == prefix)
        atomicAdd(&hist[(key >> shift) & 255], 1);
    }
    __syncthreads();
    // parallel suffix sums: suf[bin] = sum_{j>=bin} hist[j]
    if (tid < 256) suf[tid] = hist[tid];
    __syncthreads();
    for (int d = 1; d < 256; d <<= 1) {
      int t = (tid < 256 && tid + d < 256) ? suf[tid + d] : 0;
      __syncthreads();
      if (tid < 256) suf[tid] += t;
      __syncthreads();
    }
    if (tid < 256) {
      int s = suf[tid];
      int sn = (tid < 255) ? suf[tid + 1] : 0;
      if (s >= remaining && sn < remaining) {
        sh_prefix = (prefix << 8) | (unsigned)tid;
        sh_rem = remaining - sn;
      }
    }
    __syncthreads();
    prefix = sh_prefix; remaining = sh_rem;
    __syncthreads();
  }
  unsigned T = prefix;       // KEEP-th largest key; remaining = #ties to take

  const int CH2 = cKC / 1024;  // 20
  int s = tid * CH2;
  unsigned keys[CH2];
  int cntA = 0, cntT = 0;
  for (int e = 0; e < CH2; e++) {
    int c = s + e;
    unsigned key = (c < C_valid) ? f2key(ms[c]) : 0u;
    keys[e] = key;
    cntA += (key > T);
    cntT += (key == T);
  }
  int totA, totT;
  int offA = scan_excl_1024(cntA, lds, &totA);
  int offT = scan_excl_1024(cntT, lds, &totT);
  int* out = nsel + (size_t)b * cKN;
  int oa = offA, ot = offT;
  for (int e = 0; e < CH2; e++) {
    unsigned key = keys[e];
    if (key > T) { out[oa++] = s + e; }
    else if (key == T) { if (ot < remaining) out[totA + ot] = s + e; ot++; }
  }
}

// ---------------- gather negatives into G (zero unused rows) ----------------
__global__ __launch_bounds__(256) void k_gather_neg(const __hip_bfloat16* cf, const int* nsel,
                                                    const int* scal, __hip_bfloat16* G) {
  int b = blockIdx.y;
  int KEEP = scal[b * 16 + 3];
  int t = blockIdx.x * 256 + threadIdx.x;  // over cKN * 8 16B-chunks
  int k = t >> 3, part = t & 7;
  if (k >= cKN) return;
  int4 val = {0, 0, 0, 0};
  if (k < KEEP) {
    int src = nsel[(size_t)b * cKN + k];
    val = *(const int4*)((const __bf16*)(cf + (size_t)b * cKC * cC) + (size_t)src * cC + part * 8);
  }
  *(int4*)((__bf16*)(G + (size_t)b * cNT * cC) + (size_t)(cP + k) * cC + part * 8) = val;
}

// ---------------- fused loss GEMM ----------------
__global__ __launch_bounds__(256) void k_loss(const __hip_bfloat16* G, const int* scal, float* loss_sum) {
  __shared__ float sE[4][32];
  __shared__ float sL[4][32];
  int b = blockIdx.y;
  int P_valid = scal[b * 16 + 1];
  int KEEP = scal[b * 16 + 3];
  if (P_valid < 2) return;
  int wave = threadIdx.x >> 6, lane = threadIdx.x & 63;
  int lr = lane & 15, quad = lane >> 4;
  int rowbase = blockIdx.x * 32;
  const __bf16* Gb = (const __bf16*)G + (size_t)b * cNT * cC;

  bf16x8 afr[2][2];
#pragma unroll
  for (int rt = 0; rt < 2; rt++) {
    const __bf16* src = Gb + (size_t)(rowbase + rt * 16 + lr) * cC + quad * 8;
    afr[rt][0] = *(const bf16x8*)src;
    afr[rt][1] = *(const bf16x8*)(src + 32);
  }
  float eacc[2][4] = {{0, 0, 0, 0}, {0, 0, 0, 0}};
  float lacc[2][4] = {{0, 0, 0, 0}, {0, 0, 0, 0}};
  for (int ct = wave; ct < cNT / 16; ct += 4) {
    int col = ct * 16 + lr;
    const __bf16* bsrc = Gb + (size_t)col * cC + quad * 8;
    bf16x8 b0 = *(const bf16x8*)bsrc;
    bf16x8 b1 = *(const bf16x8*)(bsrc + 32);
    bool is_pos = col < cP;
    bool vcol = is_pos ? (col < P_valid) : ((col - cP) < KEEP);
#pragma unroll
    for (int rt = 0; rt < 2; rt++) {
      f32x4 acc = {0, 0, 0, 0};
      acc = __builtin_amdgcn_mfma_f32_16x16x32_bf16(afr[rt][0], b0, acc, 0, 0, 0);
      acc = __builtin_amdgcn_mfma_f32_16x16x32_bf16(afr[rt][1], b1, acc, 0, 0, 0);
      int rb = rowbase + rt * 16 + quad * 4;
#pragma unroll
      for (int r = 0; r < 4; r++) {
        float logit = acc[r] * cTEMP_INV;
        bool use = vcol && !(is_pos && (col == rb + r));
        float e = __expf(logit);
        eacc[rt][r] += use ? e : 0.0f;
        lacc[rt][r] += (use && is_pos) ? logit : 0.0f;
      }
    }
  }
#pragma unroll
  for (int rt = 0; rt < 2; rt++) {
#pragma unroll
    for (int r = 0; r < 4; r++) {
      float e = eacc[rt][r], l = lacc[rt][r];
#pragma unroll
      for (int d = 1; d < 16; d <<= 1) {
        e += __shfl_xor(e, d);
        l += __shfl_xor(l, d);
      }
      if (lr == 0) {
        sE[wave][rt * 16 + quad * 4 + r] = e;
        sL[wave][rt * 16 + quad * 4 + r] = l;
      }
    }
  }
  __syncthreads();
  if (threadIdx.x < 32) {
    int row = rowbase + threadIdx.x;
    float E = sE[0][threadIdx.x] + sE[1][threadIdx.x] + sE[2][threadIdx.x] + sE[3][threadIdx.x];
    float L = sL[0][threadIdx.x] + sL[1][threadIdx.x] + sL[2][threadIdx.x] + sL[3][threadIdx.x];
    if (row < P_valid) {
      float li = logf(E) - L / (float)(P_valid - 1);
      atomicAdd(&loss_sum[b], li);
    }
  }
}

__global__ void k_init(float* loss_sum) {
  int t = threadIdx.x;
  if (t < cB) loss_sum[t] = 0.0f;
}

__global__ void k_final(const int* scal, const float* loss_sum, float* out) {
  float tot = 0.f;
  int cnt = 0;
  for (int b = 0; b < cB; b++) {
    int Pv = scal[b * 16 + 1];
    if (Pv >= 2) { tot += loss_sum[b] / (float)Pv; cnt++; }
  }
  out[0] = tot / (float)((cnt > 0) ? cnt : 1);
}

extern "C" void kernel_launch(void* const* d_in, const int* in_sizes, int n_in,
                              void* d_out, int out_size, void* d_ws, size_t ws_size,
                              hipStream_t stream) {
  const float* feat = (const float*)d_in[0];
  const int* labels = (const int*)d_in[1];
  char* ws = (char*)d_ws;
  unsigned char* fg  = (unsigned char*)(ws + off_fg);
  unsigned char* tmp = (unsigned char*)(ws + off_tmp);
  unsigned char* rim = (unsigned char*)(ws + off_rim);
  int* pidx = (int*)(ws + off_pidx);
  int* cidx = (int*)(ws + off_cidx);
  int* scal = (int*)(ws + off_scal);
  float* loss_sum = (float*)(ws + off_loss);
  float* msim = (float*)(ws + off_msim);
  int* nsel = (int*)(ws + off_nsel);
  __hip_bfloat16* G  = (__hip_bfloat16*)(ws + off_G);
  __hip_bfloat16* cf = (__hip_bfloat16*)(ws + off_cf);
  int* blkcnt = (int*)(ws + off_bcnt);
  int2* blkoff = (int2*)(ws + off_boff);
  float* out = (float*)d_out;

  int nElem = cB * cHW;
  k_init<<<1, 64, 0, stream>>>(loss_sum);
  k_fg<<<(nElem + 255) / 256, 256, 0, stream>>>(labels, fg);
  k_hdil<<<(nElem + 255) / 256, 256, 0, stream>>>(fg, tmp);
  k_vdil_count<<<dim3(cNB, cB), 256, 0, stream>>>(tmp, fg, rim, blkcnt);
  k_offsets<<<cB, 128, 0, stream>>>(blkcnt, blkoff, scal);
  k_scatter<<<dim3(cNB, cB), 256, 0, stream>>>(fg, rim, blkoff, scal, pidx, cidx);
  k_gather_norm<<<dim3(cP / 256, cB), 256, 0, stream>>>(feat, pidx, cP, cP, G, (size_t)cNT * cC);
  k_gather_norm<<<dim3(cKC / 256, cB), 256, 0, stream>>>(feat, cidx, cKC, cKC, cf, (size_t)cKC * cC);
  k_mine<<<dim3(cKC / 128, cB), 256, 0, stream>>>(G, cf, scal, msim);
  k_selneg<<<cB, 1024, 0, stream>>>(msim, nsel, scal);
  k_gather_neg<<<dim3(cKN * 8 / 256, cB), 256, 0, stream>>>(cf, nsel, scal, G);
  k_loss<<<dim3(cP / 32, cB), 256, 0, stream>>>(G, scal, loss_sum);
  k_final<<<1, 1, 0, stream>>>(scal, loss_sum, out);
}

// Round 3
// 416.908 us; speedup vs baseline: 1.6001x; 1.1463x over previous
//
#include <hip/hip_runtime.h>
#include <hip/hip_bf16.h>

#define DEVI __device__ __forceinline__

static constexpr int cB = 4, cC = 64, cH = 384, cW = 384;
static constexpr int cHW = cH * cW;           // 147456
static constexpr int cP  = 2048;              // MAX_POS
static constexpr int cKC = 20480;             // candidate pool
static constexpr int cKN = 10240;             // max negatives
static constexpr int cNT = cP + cKN;          // 12288 rows of G = [pf; nf]
static constexpr float cTEMP_INV = 10.0f;     // 1/TEMP
static constexpr int cCHUNK = 2048;           // elems per selection block
static constexpr int cNB = cHW / cCHUNK;      // 72 selection blocks per image
static constexpr int cNCH = 8;                // column chunks for k_loss_part
static constexpr int cTPC = (cNT / 16) / cNCH; // 96 col tiles per chunk

using f32x4  = __attribute__((ext_vector_type(4))) float;
using bf16x8 = __attribute__((ext_vector_type(8))) __bf16;

// ---- workspace layout (bytes) ----
static constexpr size_t off_fg   = 0;
static constexpr size_t off_tmp  = off_fg   + (size_t)cB * cHW;
static constexpr size_t off_rim  = off_tmp  + (size_t)cB * cHW;
static constexpr size_t off_pidx = off_rim  + (size_t)cB * cHW;
static constexpr size_t off_cidx = off_pidx + (size_t)cB * cP * 4;
static constexpr size_t off_scal = off_cidx + (size_t)cB * cKC * 4;
static constexpr size_t off_EL   = off_scal + 256;                        // float2 per (b,row)
static constexpr size_t off_msim = off_EL   + (size_t)cB * cP * 8;        // 2 row-chunks
static constexpr size_t off_nsel = off_msim + (size_t)cB * 2 * cKC * 4;
static constexpr size_t off_G    = off_nsel + (size_t)cB * cKN * 4;
static constexpr size_t off_cf   = off_G    + (size_t)cB * cNT * cC * 2;
static constexpr size_t off_bcnt = off_cf   + (size_t)cB * cKC * cC * 2;
static constexpr size_t off_boff = off_bcnt + (size_t)cB * cNB * 4;
// total ≈ 19.8 MB

// ---------------- masks ----------------
__global__ void k_fg(const int* labels, unsigned char* fg) {
  int i = blockIdx.x * 256 + threadIdx.x;
  if (i < cB * cHW) fg[i] = labels[i] > 0;
}

__global__ void k_hdil(const unsigned char* fg, unsigned char* tmp) {
  int i = blockIdx.x * 256 + threadIdx.x;
  if (i >= cB * cHW) return;
  int x = i % cW;
  int rowbase = i - x;
  int lo = max(x - 5, 0), hi = min(x + 5, cW - 1);
  unsigned char m = 0;
  for (int xx = lo; xx <= hi; xx++) m |= fg[rowbase + xx];
  tmp[i] = m;
}

// vertical dilation + rim + per-block packed counts (fg | rim<<16)
__global__ __launch_bounds__(256) void k_vdil_count(const unsigned char* tmp, const unsigned char* fg,
                                                    unsigned char* rim, int* blkcnt) {
  __shared__ int red[256];
  int b = blockIdx.y, blk = blockIdx.x, tid = threadIdx.x;
  int base = blk * cCHUNK + tid * 8;
  const unsigned char* tb  = tmp + (size_t)b * cHW;
  const unsigned char* fgb = fg  + (size_t)b * cHW;
  unsigned long long fv = *(const unsigned long long*)(fgb + base);
  unsigned long long pk = 0;
  int crim = 0;
#pragma unroll
  for (int e = 0; e < 8; e++) {
    int p = base + e;
    int y = p / cW, x = p - y * cW;
    int lo = max(y - 5, 0), hi = min(y + 5, cH - 1);
    unsigned char m = 0;
    for (int yy = lo; yy <= hi; yy++) m |= tb[yy * cW + x];
    unsigned char f = (unsigned char)((fv >> (8 * e)) & 1);
    unsigned char rv = m & (f ^ 1);
    pk |= (unsigned long long)rv << (8 * e);
    crim += rv;
  }
  *(unsigned long long*)(rim + (size_t)b * cHW + base) = pk;
  int cfg = __popcll(fv & 0x0101010101010101ULL);
  red[tid] = cfg | (crim << 16);
  __syncthreads();
  for (int s = 128; s > 0; s >>= 1) {
    if (tid < s) red[tid] += red[tid + s];
    __syncthreads();
  }
  if (tid == 0) blkcnt[b * cNB + blk] = red[0];
}

// per-image exclusive scan over the 72 block counts
__global__ __launch_bounds__(128) void k_offsets(const int* blkcnt, int2* blkoff, int* scal) {
  __shared__ int sf[128], sr[128];
  int b = blockIdx.x, tid = threadIdx.x;
  int v = (tid < cNB) ? blkcnt[b * cNB + tid] : 0;
  int f = v & 0xffff, r = v >> 16;
  sf[tid] = f; sr[tid] = r;
  __syncthreads();
  for (int d = 1; d < 128; d <<= 1) {
    int tf = (tid >= d) ? sf[tid - d] : 0;
    int tr = (tid >= d) ? sr[tid - d] : 0;
    __syncthreads();
    sf[tid] += tf; sr[tid] += tr;
    __syncthreads();
  }
  if (tid < cNB) blkoff[b * cNB + tid] = make_int2(sf[tid] - f, sr[tid] - r);
  if (tid == 0) {
    int nfg = sf[cNB - 1], nrim = sr[cNB - 1];
    scal[b * 16 + 0] = nfg;
    scal[b * 16 + 1] = min(nfg, cP);    // P_valid
    scal[b * 16 + 2] = min(nrim, cKC);  // C_valid
    scal[b * 16 + 4] = nrim;
  }
}

__device__ int scan_excl_256(int v, int* lds) {
  int tid = threadIdx.x;
  lds[tid] = v;
  __syncthreads();
  for (int d = 1; d < 256; d <<= 1) {
    int t = (tid >= d) ? lds[tid - d] : 0;
    __syncthreads();
    lds[tid] += t;
    __syncthreads();
  }
  int e = lds[tid] - v;
  __syncthreads();
  return e;
}

// raster-order scatter: fg->pidx (fill !fg), rim->cidx (fill !rim)
__global__ __launch_bounds__(256) void k_scatter(const unsigned char* fg, const unsigned char* rim,
                                                 const int2* blkoff, const int* scal,
                                                 int* pidx, int* cidx) {
  __shared__ int lds[256];
  int b = blockIdx.y, blk = blockIdx.x, tid = threadIdx.x;
  int2 off = blkoff[b * cNB + blk];
  int nfg  = scal[b * 16 + 0];
  int nrim = scal[b * 16 + 4];
  bool needf = (off.x < cP)  || (nfg  < cP);
  bool needr = (off.y < cKC) || (nrim < cKC);
  if (!needf && !needr) return;
  int base = blk * cCHUNK + tid * 8;
  const unsigned char* fgb  = fg  + (size_t)b * cHW;
  const unsigned char* rimb = rim + (size_t)b * cHW;
  unsigned long long fv = *(const unsigned long long*)(fgb + base);
  unsigned long long rv = *(const unsigned long long*)(rimb + base);
  int cfg  = __popcll(fv & 0x0101010101010101ULL);
  int crim = __popcll(rv & 0x0101010101010101ULL);
  int ex = scan_excl_256(cfg | (crim << 16), lds);
  int of  = off.x + (ex & 0xffff);
  int orr = off.y + (ex >> 16);
  int* pout = pidx + (size_t)b * cP;
  int* cout = cidx + (size_t)b * cKC;
#pragma unroll
  for (int e = 0; e < 8; e++) {
    int p = base + e;
    int f = (int)((fv >> (8 * e)) & 1);
    int r = (int)((rv >> (8 * e)) & 1);
    if (f) { if (of < cP) pout[of] = p; of++; }
    else if (nfg < cP) { int o = nfg + (p - of); if (o < cP) pout[o] = p; }
    if (r) { if (orr < cKC) cout[orr] = p; orr++; }
    else if (nrim < cKC) { int o = nrim + (p - orr); if (o < cKC) cout[o] = p; }
  }
}

// ---------------- gather + L2-normalize -> bf16 rows ----------------
__global__ __launch_bounds__(256) void k_gather_norm(const float* feat, const int* idxs, int idx_stride,
                                                     int count, __hip_bfloat16* dst, size_t dst_img_stride) {
  int b = blockIdx.y;
  int i = blockIdx.x * 256 + threadIdx.x;
  if (i >= count) return;
  int p = idxs[(size_t)b * idx_stride + i];
  const float* fb = feat + (size_t)b * cC * cHW + p;
  float v[cC];
  float ss = 0.f;
#pragma unroll
  for (int c = 0; c < cC; c++) { float t = fb[(size_t)c * cHW]; v[c] = t; ss += t * t; }
  float sc = 1.0f / fmaxf(sqrtf(ss), 1e-8f);
  __hip_bfloat16* out = dst + (size_t)b * dst_img_stride + (size_t)i * cC;
#pragma unroll
  for (int c = 0; c < cC; c++) out[c] = __float2bfloat16(v[c] * sc);
}

// ---------------- hard-negative mining: column max of pf @ cf^T (row-chunked) ----------------
__global__ __launch_bounds__(256) void k_mine(const __hip_bfloat16* G, const __hip_bfloat16* cf,
                                              const int* scal, float* msim) {
  int b = blockIdx.z, rc = blockIdx.y;
  int P_valid = scal[b * 16 + 1];
  int wave = threadIdx.x >> 6, lane = threadIdx.x & 63;
  int lr = lane & 15, quad = lane >> 4;
  int colbase = blockIdx.x * 128 + wave * 32;
  float* msout = msim + ((size_t)b * 2 + rc) * cKC;
  int mt0 = rc * (cP / 32);           // 64 row tiles per chunk
  int chunk_lo = mt0 * 16;
  if (chunk_lo >= P_valid) {          // whole chunk invalid
    if (quad == 0) {
      msout[colbase + lr]      = -INFINITY;
      msout[colbase + 16 + lr] = -INFINITY;
    }
    return;
  }
  bool chunk_full = (chunk_lo + cP / 2) <= P_valid;
  const __bf16* pf  = (const __bf16*)(G  + (size_t)b * cNT * cC);
  const __bf16* cfb = (const __bf16*)(cf + (size_t)b * cKC * cC);

  bf16x8 bfr[2][2];
#pragma unroll
  for (int t = 0; t < 2; t++) {
    const __bf16* src = cfb + (size_t)(colbase + t * 16 + lr) * cC + quad * 8;
    bfr[t][0] = *(const bf16x8*)src;
    bfr[t][1] = *(const bf16x8*)(src + 32);
  }
  float cmax0 = -INFINITY, cmax1 = -INFINITY;
#pragma unroll 2
  for (int mt = mt0; mt < mt0 + cP / 32; mt++) {
    const __bf16* asrc = pf + (size_t)(mt * 16 + lr) * cC + quad * 8;
    bf16x8 a0 = *(const bf16x8*)asrc;
    bf16x8 a1 = *(const bf16x8*)(asrc + 32);
    f32x4 acc0 = {0, 0, 0, 0}, acc1 = {0, 0, 0, 0};
    acc0 = __builtin_amdgcn_mfma_f32_16x16x32_bf16(a0, bfr[0][0], acc0, 0, 0, 0);
    acc0 = __builtin_amdgcn_mfma_f32_16x16x32_bf16(a1, bfr[0][1], acc0, 0, 0, 0);
    acc1 = __builtin_amdgcn_mfma_f32_16x16x32_bf16(a0, bfr[1][0], acc1, 0, 0, 0);
    acc1 = __builtin_amdgcn_mfma_f32_16x16x32_bf16(a1, bfr[1][1], acc1, 0, 0, 0);
    if (chunk_full) {
#pragma unroll
      for (int r = 0; r < 4; r++) {
        cmax0 = fmaxf(cmax0, acc0[r]);
        cmax1 = fmaxf(cmax1, acc1[r]);
      }
    } else {
      int rb = mt * 16 + quad * 4;
#pragma unroll
      for (int r = 0; r < 4; r++) {
        bool rv = (rb + r) < P_valid;
        cmax0 = fmaxf(cmax0, rv ? acc0[r] : -INFINITY);
        cmax1 = fmaxf(cmax1, rv ? acc1[r] : -INFINITY);
      }
    }
  }
  cmax0 = fmaxf(cmax0, __shfl_xor(cmax0, 16));
  cmax0 = fmaxf(cmax0, __shfl_xor(cmax0, 32));
  cmax1 = fmaxf(cmax1, __shfl_xor(cmax1, 16));
  cmax1 = fmaxf(cmax1, __shfl_xor(cmax1, 32));
  if (quad == 0) {
    msout[colbase + lr]      = cmax0;
    msout[colbase + 16 + lr] = cmax1;
  }
}

// ---------------- top-KEEP selection (radix threshold; set semantics) ----------------
DEVI unsigned f2key(float f) {
  unsigned u = __float_as_uint(f);
  return (u & 0x80000000u) ? ~u : (u | 0x80000000u);
}

__device__ int scan_excl_1024(int v, int* lds, int* total) {
  int tid = threadIdx.x;
  lds[tid] = v;
  __syncthreads();
  for (int d = 1; d < 1024; d <<= 1) {
    int t = (tid >= d) ? lds[tid - d] : 0;
    __syncthreads();
    lds[tid] += t;
    __syncthreads();
  }
  *total = lds[1023];
  int e = lds[tid] - v;
  __syncthreads();
  return e;
}

__global__ __launch_bounds__(1024) void k_selneg(const float* msim, int* nsel, int* scal) {
  __shared__ int hist[256];
  __shared__ int suf[256];
  __shared__ int lds[1024];
  __shared__ unsigned sh_prefix;
  __shared__ int sh_rem;
  int b = blockIdx.x, tid = threadIdx.x;
  const float* ms0 = msim + ((size_t)b * 2 + 0) * cKC;
  const float* ms1 = msim + ((size_t)b * 2 + 1) * cKC;
  int P_valid = scal[b * 16 + 1], C_valid = scal[b * 16 + 2];
  int n_allowed = min(5 * P_valid, cKN);
  int nfin = (P_valid > 0) ? C_valid : 0;
  int KEEP = min(n_allowed, nfin);
  if (tid == 0) scal[b * 16 + 3] = KEEP;
  if (KEEP == 0) return;

  unsigned prefix = 0;
  int remaining = KEEP;
  for (int shift = 24; shift >= 0; shift -= 8) {
    if (tid < 256) hist[tid] = 0;
    __syncthreads();
    for (int c = tid; c < cKC; c += 1024) {
      unsigned key = (c < C_valid) ? f2key(fmaxf(ms0[c], ms1[c])) : 0u;
      if (shift == 24 || (key >> (shift + 8)) == prefix)
        atomicAdd(&hist[(key >> shift) & 255], 1);
    }
    __syncthreads();
    if (tid < 256) suf[tid] = hist[tid];
    __syncthreads();
    for (int d = 1; d < 256; d <<= 1) {
      int t = (tid < 256 && tid + d < 256) ? suf[tid + d] : 0;
      __syncthreads();
      if (tid < 256) suf[tid] += t;
      __syncthreads();
    }
    if (tid < 256) {
      int s = suf[tid];
      int sn = (tid < 255) ? suf[tid + 1] : 0;
      if (s >= remaining && sn < remaining) {
        sh_prefix = (prefix << 8) | (unsigned)tid;
        sh_rem = remaining - sn;
      }
    }
    __syncthreads();
    prefix = sh_prefix; remaining = sh_rem;
    __syncthreads();
  }
  unsigned T = prefix;

  const int CH2 = cKC / 1024;  // 20
  int s = tid * CH2;
  unsigned keys[CH2];
  int cntA = 0, cntT = 0;
  for (int e = 0; e < CH2; e++) {
    int c = s + e;
    unsigned key = (c < C_valid) ? f2key(fmaxf(ms0[c], ms1[c])) : 0u;
    keys[e] = key;
    cntA += (key > T);
    cntT += (key == T);
  }
  int totA, totT;
  int offA = scan_excl_1024(cntA, lds, &totA);
  int offT = scan_excl_1024(cntT, lds, &totT);
  int* out = nsel + (size_t)b * cKN;
  int oa = offA, ot = offT;
  for (int e = 0; e < CH2; e++) {
    unsigned key = keys[e];
    if (key > T) { out[oa++] = s + e; }
    else if (key == T) { if (ot < remaining) out[totA + ot] = s + e; ot++; }
  }
}

// ---------------- gather negatives into G (zero unused rows) ----------------
__global__ __launch_bounds__(256) void k_gather_neg(const __hip_bfloat16* cf, const int* nsel,
                                                    const int* scal, __hip_bfloat16* G) {
  int b = blockIdx.y;
  int KEEP = scal[b * 16 + 3];
  int t = blockIdx.x * 256 + threadIdx.x;
  int k = t >> 3, part = t & 7;
  if (k >= cKN) return;
  int4 val = {0, 0, 0, 0};
  if (k < KEEP) {
    int src = nsel[(size_t)b * cKN + k];
    val = *(const int4*)((const __bf16*)(cf + (size_t)b * cKC * cC) + (size_t)src * cC + part * 8);
  }
  *(int4*)((__bf16*)(G + (size_t)b * cNT * cC) + (size_t)(cP + k) * cC + part * 8) = val;
}

// ---------------- fused loss GEMM (column-chunked, atomic E/L accumulation) ----------------
__global__ __launch_bounds__(256) void k_loss_part(const __hip_bfloat16* G, const int* scal, float2* EL) {
  __shared__ float sE[4][32];
  __shared__ float sL[4][32];
  int b = blockIdx.z;
  int P_valid = scal[b * 16 + 1];
  int KEEP = scal[b * 16 + 3];
  int wave = threadIdx.x >> 6, lane = threadIdx.x & 63;
  int lr = lane & 15, quad = lane >> 4;
  int rowbase = blockIdx.x * 32;
  const __bf16* Gb = (const __bf16*)G + (size_t)b * cNT * cC;

  bf16x8 afr[2][2];
#pragma unroll
  for (int rt = 0; rt < 2; rt++) {
    const __bf16* src = Gb + (size_t)(rowbase + rt * 16 + lr) * cC + quad * 8;
    afr[rt][0] = *(const bf16x8*)src;
    afr[rt][1] = *(const bf16x8*)(src + 32);
  }
  float eacc[2][4] = {{0, 0, 0, 0}, {0, 0, 0, 0}};
  float lacc[2][4] = {{0, 0, 0, 0}, {0, 0, 0, 0}};
  int ct0 = blockIdx.y * cTPC;
  for (int ct = ct0 + wave; ct < ct0 + cTPC; ct += 4) {
    int tb = ct * 16;
    bool is_pos = tb < cP;
    int vlimit = is_pos ? P_valid : (cP + KEEP);
    if (tb >= vlimit) continue;                       // wave-uniform skip
    bool all_valid = (tb + 16) <= vlimit;
    bool has_diag = is_pos && (tb >= rowbase) && (tb < rowbase + 32);
    const __bf16* bsrc = Gb + (size_t)(tb + lr) * cC + quad * 8;
    bf16x8 b0 = *(const bf16x8*)bsrc;
    bf16x8 b1 = *(const bf16x8*)(bsrc + 32);
    f32x4 acc[2];
#pragma unroll
    for (int rt = 0; rt < 2; rt++) {
      f32x4 a = {0, 0, 0, 0};
      a = __builtin_amdgcn_mfma_f32_16x16x32_bf16(afr[rt][0], b0, a, 0, 0, 0);
      a = __builtin_amdgcn_mfma_f32_16x16x32_bf16(afr[rt][1], b1, a, 0, 0, 0);
      acc[rt] = a;
    }
    if (all_valid && !has_diag) {
      if (is_pos) {
#pragma unroll
        for (int rt = 0; rt < 2; rt++)
#pragma unroll
          for (int r = 0; r < 4; r++) {
            float logit = acc[rt][r] * cTEMP_INV;
            eacc[rt][r] += __expf(logit);
            lacc[rt][r] += logit;
          }
      } else {
#pragma unroll
        for (int rt = 0; rt < 2; rt++)
#pragma unroll
          for (int r = 0; r < 4; r++)
            eacc[rt][r] += __expf(acc[rt][r] * cTEMP_INV);
      }
    } else {
      bool colv = (tb + lr) < vlimit;
#pragma unroll
      for (int rt = 0; rt < 2; rt++) {
        int rb = rowbase + rt * 16 + quad * 4;
#pragma unroll
        for (int r = 0; r < 4; r++) {
          float logit = acc[rt][r] * cTEMP_INV;
          bool use = colv && !(has_diag && (tb + lr) == (rb + r));
          float e = __expf(logit);
          eacc[rt][r] += use ? e : 0.0f;
          if (is_pos) lacc[rt][r] += use ? logit : 0.0f;
        }
      }
    }
  }
#pragma unroll
  for (int rt = 0; rt < 2; rt++) {
#pragma unroll
    for (int r = 0; r < 4; r++) {
      float e = eacc[rt][r], l = lacc[rt][r];
#pragma unroll
      for (int d = 1; d < 16; d <<= 1) {
        e += __shfl_xor(e, d);
        l += __shfl_xor(l, d);
      }
      if (lr == 0) {
        sE[wave][rt * 16 + quad * 4 + r] = e;
        sL[wave][rt * 16 + quad * 4 + r] = l;
      }
    }
  }
  __syncthreads();
  if (threadIdx.x < 32) {
    int row = rowbase + threadIdx.x;
    float E = sE[0][threadIdx.x] + sE[1][threadIdx.x] + sE[2][threadIdx.x] + sE[3][threadIdx.x];
    float L = sL[0][threadIdx.x] + sL[1][threadIdx.x] + sL[2][threadIdx.x] + sL[3][threadIdx.x];
    atomicAdd(&EL[(size_t)b * cP + row].x, E);
    atomicAdd(&EL[(size_t)b * cP + row].y, L);
  }
}

// ---------------- finalize: per-row loss, per-image mean, cross-image mean ----------------
__global__ __launch_bounds__(1024) void k_loss_fin(const int* scal, const float2* EL, float* out) {
  __shared__ float ssum[16];
  int tid = threadIdx.x;
  int b = tid >> 8, t = tid & 255;
  int Pv = scal[b * 16 + 1];
  float s = 0.f;
  if (Pv >= 2) {
    float inv = 1.0f / (float)(Pv - 1);
#pragma unroll
    for (int e = 0; e < 8; e++) {
      int row = t * 8 + e;
      if (row < Pv) {
        float2 el = EL[(size_t)b * cP + row];
        s += logf(el.x) - el.y * inv;
      }
    }
  }
#pragma unroll
  for (int d = 1; d < 64; d <<= 1) s += __shfl_xor(s, d);
  if ((tid & 63) == 0) ssum[tid >> 6] = s;
  __syncthreads();
  if (tid == 0) {
    float tot = 0.f;
    int cnt = 0;
    for (int bb = 0; bb < cB; bb++) {
      int P = scal[bb * 16 + 1];
      if (P >= 2) {
        float is = ssum[bb * 4] + ssum[bb * 4 + 1] + ssum[bb * 4 + 2] + ssum[bb * 4 + 3];
        tot += is / (float)P;
        cnt++;
      }
    }
    out[0] = tot / (float)(cnt > 0 ? cnt : 1);
  }
}

extern "C" void kernel_launch(void* const* d_in, const int* in_sizes, int n_in,
                              void* d_out, int out_size, void* d_ws, size_t ws_size,
                              hipStream_t stream) {
  const float* feat = (const float*)d_in[0];
  const int* labels = (const int*)d_in[1];
  char* ws = (char*)d_ws;
  unsigned char* fg  = (unsigned char*)(ws + off_fg);
  unsigned char* tmp = (unsigned char*)(ws + off_tmp);
  unsigned char* rim = (unsigned char*)(ws + off_rim);
  int* pidx = (int*)(ws + off_pidx);
  int* cidx = (int*)(ws + off_cidx);
  int* scal = (int*)(ws + off_scal);
  float2* EL = (float2*)(ws + off_EL);
  float* msim = (float*)(ws + off_msim);
  int* nsel = (int*)(ws + off_nsel);
  __hip_bfloat16* G  = (__hip_bfloat16*)(ws + off_G);
  __hip_bfloat16* cf = (__hip_bfloat16*)(ws + off_cf);
  int* blkcnt = (int*)(ws + off_bcnt);
  int2* blkoff = (int2*)(ws + off_boff);
  float* out = (float*)d_out;

  int nElem = cB * cHW;
  hipMemsetAsync(EL, 0, (size_t)cB * cP * 8, stream);
  k_fg<<<(nElem + 255) / 256, 256, 0, stream>>>(labels, fg);
  k_hdil<<<(nElem + 255) / 256, 256, 0, stream>>>(fg, tmp);
  k_vdil_count<<<dim3(cNB, cB), 256, 0, stream>>>(tmp, fg, rim, blkcnt);
  k_offsets<<<cB, 128, 0, stream>>>(blkcnt, blkoff, scal);
  k_scatter<<<dim3(cNB, cB), 256, 0, stream>>>(fg, rim, blkoff, scal, pidx, cidx);
  k_gather_norm<<<dim3(cP / 256, cB), 256, 0, stream>>>(feat, pidx, cP, cP, G, (size_t)cNT * cC);
  k_gather_norm<<<dim3(cKC / 256, cB), 256, 0, stream>>>(feat, cidx, cKC, cKC, cf, (size_t)cKC * cC);
  k_mine<<<dim3(cKC / 128, 2, cB), 256, 0, stream>>>(G, cf, scal, msim);
  k_selneg<<<cB, 1024, 0, stream>>>(msim, nsel, scal);
  k_gather_neg<<<dim3(cKN * 8 / 256, cB), 256, 0, stream>>>(cf, nsel, scal, G);
  k_loss_part<<<dim3(cP / 32, cNCH, cB), 256, 0, stream>>>(G, scal, EL);
  k_loss_fin<<<1, 1024, 0, stream>>>(scal, EL, out);
}

// Round 4
// 369.980 us; speedup vs baseline: 1.8031x; 1.1268x over previous
//
#include <hip/hip_runtime.h>
#include <hip/hip_bf16.h>

#define DEVI __device__ __forceinline__

static constexpr int cB = 4, cC = 64, cH = 384, cW = 384;
static constexpr int cHW = cH * cW;           // 147456
static constexpr int cP  = 2048;              // MAX_POS
static constexpr int cKC = 20480;             // candidate pool
static constexpr int cKN = 10240;             // max negatives
static constexpr int cNT = cP + cKN;          // 12288 rows of G = [pf; nf]
static constexpr float cTEMP_INV = 10.0f;     // 1/TEMP
static constexpr int cCHUNK = 2048;           // elems per selection block
static constexpr int cNB = cHW / cCHUNK;      // 72 selection blocks per image
static constexpr int cNCH = 8;                // column chunks for k_loss_part
static constexpr int cTPC = (cNT / 16) / cNCH; // 96 col tiles per chunk

using f32x4  = __attribute__((ext_vector_type(4))) float;
using bf16x8 = __attribute__((ext_vector_type(8))) __bf16;

// ---- workspace layout (bytes) ----
static constexpr size_t off_fg   = 0;
static constexpr size_t off_tmp  = off_fg   + (size_t)cB * cHW;
static constexpr size_t off_rim  = off_tmp  + (size_t)cB * cHW;
static constexpr size_t off_pidx = off_rim  + (size_t)cB * cHW;
static constexpr size_t off_cidx = off_pidx + (size_t)cB * cP * 4;
static constexpr size_t off_scal = off_cidx + (size_t)cB * cKC * 4;
static constexpr size_t off_EL   = off_scal + 256;                        // float2 per (chunk,b,row)
static constexpr size_t off_msim = off_EL   + (size_t)cNCH * cB * cP * 8;
static constexpr size_t off_nsel = off_msim + (size_t)cB * 2 * cKC * 4;
static constexpr size_t off_G    = off_nsel + (size_t)cB * cKN * 4;
static constexpr size_t off_cf   = off_G    + (size_t)cB * cNT * cC * 2;
static constexpr size_t off_bcnt = off_cf   + (size_t)cB * cKC * cC * 2;
static constexpr size_t off_boff = off_bcnt + (size_t)cB * cNB * 4;
// total ≈ 20.3 MB

DEVI f32x4 mfma16(bf16x8 a, bf16x8 b, f32x4 c) {
  return __builtin_amdgcn_mfma_f32_16x16x32_bf16(a, b, c, 0, 0, 0);
}

// ---------------- fused fg + horizontal dilation (bit-window) ----------------
__global__ __launch_bounds__(256) void k_fg_hdil(const int* labels, unsigned char* fg, unsigned char* tmp) {
  int t = blockIdx.x * 256 + threadIdx.x;   // over cB*cHW/8
  int base = t * 8;                          // 8 px per thread, within one row (8 | 384)
  int x0 = base % cW;
  const int* lb = labels + (base - x0);      // row start
  unsigned m = 0;
#pragma unroll
  for (int j = 0; j < 18; j++) {
    int x = x0 - 5 + j;
    int v = (x >= 0 && x < cW) ? (lb[x] > 0) : 0;
    m |= (unsigned)v << j;
  }
  unsigned long long fgb = 0, tmb = 0;
#pragma unroll
  for (int e = 0; e < 8; e++) {
    fgb |= (unsigned long long)((m >> (e + 5)) & 1u) << (8 * e);
    tmb |= (unsigned long long)(((m >> e) & 0x7FFu) ? 1u : 0u) << (8 * e);
  }
  *(unsigned long long*)(fg + base)  = fgb;
  *(unsigned long long*)(tmp + base) = tmb;
}

// vertical dilation + rim + per-block packed counts (fg | rim<<16)
__global__ __launch_bounds__(256) void k_vdil_count(const unsigned char* tmp, const unsigned char* fg,
                                                    unsigned char* rim, int* blkcnt) {
  __shared__ int red[256];
  int b = blockIdx.y, blk = blockIdx.x, tid = threadIdx.x;
  int base = blk * cCHUNK + tid * 8;         // within one row (8 | 384)
  const unsigned char* tb  = tmp + (size_t)b * cHW;
  const unsigned char* fgb = fg  + (size_t)b * cHW;
  unsigned long long fv = *(const unsigned long long*)(fgb + base);
  int y = base / cW, x = base % cW;
  int lo = max(y - 5, 0), hi = min(y + 5, cH - 1);
  unsigned long long m8 = 0;
  for (int yy = lo; yy <= hi; yy++) m8 |= *(const unsigned long long*)(tb + yy * cW + x);
  unsigned long long pk = m8 & (fv ^ 0x0101010101010101ULL);
  *(unsigned long long*)(rim + (size_t)b * cHW + base) = pk;
  int cfg  = __popcll(fv & 0x0101010101010101ULL);
  int crim = __popcll(pk & 0x0101010101010101ULL);
  red[tid] = cfg | (crim << 16);
  __syncthreads();
  for (int s = 128; s > 0; s >>= 1) {
    if (tid < s) red[tid] += red[tid + s];
    __syncthreads();
  }
  if (tid == 0) blkcnt[b * cNB + blk] = red[0];
}

// per-image exclusive scan over the 72 block counts
__global__ __launch_bounds__(128) void k_offsets(const int* blkcnt, int2* blkoff, int* scal) {
  __shared__ int sf[128], sr[128];
  int b = blockIdx.x, tid = threadIdx.x;
  int v = (tid < cNB) ? blkcnt[b * cNB + tid] : 0;
  int f = v & 0xffff, r = v >> 16;
  sf[tid] = f; sr[tid] = r;
  __syncthreads();
  for (int d = 1; d < 128; d <<= 1) {
    int tf = (tid >= d) ? sf[tid - d] : 0;
    int tr = (tid >= d) ? sr[tid - d] : 0;
    __syncthreads();
    sf[tid] += tf; sr[tid] += tr;
    __syncthreads();
  }
  if (tid < cNB) blkoff[b * cNB + tid] = make_int2(sf[tid] - f, sr[tid] - r);
  if (tid == 0) {
    int nfg = sf[cNB - 1], nrim = sr[cNB - 1];
    scal[b * 16 + 0] = nfg;
    scal[b * 16 + 1] = min(nfg, cP);    // P_valid
    scal[b * 16 + 2] = min(nrim, cKC);  // C_valid
    scal[b * 16 + 4] = nrim;
  }
}

__device__ int scan_excl_256(int v, int* lds) {
  int tid = threadIdx.x;
  lds[tid] = v;
  __syncthreads();
  for (int d = 1; d < 256; d <<= 1) {
    int t = (tid >= d) ? lds[tid - d] : 0;
    __syncthreads();
    lds[tid] += t;
    __syncthreads();
  }
  int e = lds[tid] - v;
  __syncthreads();
  return e;
}

// raster-order scatter: fg->pidx (fill !fg), rim->cidx (fill !rim)
__global__ __launch_bounds__(256) void k_scatter(const unsigned char* fg, const unsigned char* rim,
                                                 const int2* blkoff, const int* scal,
                                                 int* pidx, int* cidx) {
  __shared__ int lds[256];
  int b = blockIdx.y, blk = blockIdx.x, tid = threadIdx.x;
  int2 off = blkoff[b * cNB + blk];
  int nfg  = scal[b * 16 + 0];
  int nrim = scal[b * 16 + 4];
  bool needf = (off.x < cP)  || (nfg  < cP);
  bool needr = (off.y < cKC) || (nrim < cKC);
  if (!needf && !needr) return;
  int base = blk * cCHUNK + tid * 8;
  const unsigned char* fgb  = fg  + (size_t)b * cHW;
  const unsigned char* rimb = rim + (size_t)b * cHW;
  unsigned long long fv = *(const unsigned long long*)(fgb + base);
  unsigned long long rv = *(const unsigned long long*)(rimb + base);
  int cfg  = __popcll(fv & 0x0101010101010101ULL);
  int crim = __popcll(rv & 0x0101010101010101ULL);
  int ex = scan_excl_256(cfg | (crim << 16), lds);
  int of  = off.x + (ex & 0xffff);
  int orr = off.y + (ex >> 16);
  int* pout = pidx + (size_t)b * cP;
  int* cout = cidx + (size_t)b * cKC;
#pragma unroll
  for (int e = 0; e < 8; e++) {
    int p = base + e;
    int f = (int)((fv >> (8 * e)) & 1);
    int r = (int)((rv >> (8 * e)) & 1);
    if (f) { if (of < cP) pout[of] = p; of++; }
    else if (nfg < cP) { int o = nfg + (p - of); if (o < cP) pout[o] = p; }
    if (r) { if (orr < cKC) cout[orr] = p; orr++; }
    else if (nrim < cKC) { int o = nrim + (p - orr); if (o < cKC) cout[o] = p; }
  }
}

// ---------------- gather + L2-normalize -> bf16 rows (both pools, one launch) ----------------
__global__ __launch_bounds__(256) void k_gather_norm(const float* feat, const int* pidx, const int* cidx,
                                                     __hip_bfloat16* G, __hip_bfloat16* cf) {
  int b = blockIdx.y;
  int bx = blockIdx.x;
  int p;
  __hip_bfloat16* out;
  if (bx < cP / 256) {
    int i = bx * 256 + threadIdx.x;
    p = pidx[(size_t)b * cP + i];
    out = G + (size_t)b * cNT * cC + (size_t)i * cC;
  } else {
    int i = (bx - cP / 256) * 256 + threadIdx.x;
    p = cidx[(size_t)b * cKC + i];
    out = cf + (size_t)b * cKC * cC + (size_t)i * cC;
  }
  const float* fb = feat + (size_t)b * cC * cHW + p;
  float v[cC];
  float ss = 0.f;
#pragma unroll
  for (int c = 0; c < cC; c++) { float t = fb[(size_t)c * cHW]; v[c] = t; ss += t * t; }
  float sc = 1.0f / fmaxf(sqrtf(ss), 1e-8f);
#pragma unroll
  for (int c = 0; c < cC; c++) out[c] = __float2bfloat16(v[c] * sc);
}

// ---------------- hard-negative mining: column max of pf @ cf^T ----------------
// 128 cols per wave, 512 per block; A streamed with prefetch (row-chunked over 2 chunks)
__global__ __launch_bounds__(256) void k_mine(const __hip_bfloat16* G, const __hip_bfloat16* cf,
                                              const int* scal, float* msim) {
  int b = blockIdx.z, rc = blockIdx.y;
  int P_valid = scal[b * 16 + 1];
  int wave = threadIdx.x >> 6, lane = threadIdx.x & 63;
  int lr = lane & 15, quad = lane >> 4;
  int colbase = (blockIdx.x * 4 + wave) * 128;
  float* msout = msim + ((size_t)b * 2 + rc) * cKC;
  int mt0 = rc * 64;
  int chunk_lo = mt0 * 16;
  if (chunk_lo >= P_valid) {
    if (quad == 0) {
#pragma unroll
      for (int tt = 0; tt < 8; tt++) msout[colbase + tt * 16 + lr] = -INFINITY;
    }
    return;
  }
  bool chunk_full = (chunk_lo + 1024) <= P_valid;
  const __bf16* pf  = (const __bf16*)(G  + (size_t)b * cNT * cC);
  const __bf16* cfb = (const __bf16*)(cf + (size_t)b * cKC * cC);

  bf16x8 bfr[8][2];
#pragma unroll
  for (int tt = 0; tt < 8; tt++) {
    const __bf16* src = cfb + (size_t)(colbase + tt * 16 + lr) * cC + quad * 8;
    bfr[tt][0] = *(const bf16x8*)src;
    bfr[tt][1] = *(const bf16x8*)(src + 32);
  }
  float cmax[8];
#pragma unroll
  for (int tt = 0; tt < 8; tt++) cmax[tt] = -INFINITY;

  const __bf16* ap = pf + (size_t)(mt0 * 16 + lr) * cC + quad * 8;
  bf16x8 a0 = *(const bf16x8*)ap;
  bf16x8 a1 = *(const bf16x8*)(ap + 32);
  for (int mt = mt0; mt < mt0 + 64; mt++) {
    int nmt = min(mt + 1, mt0 + 63);
    const __bf16* np = pf + (size_t)(nmt * 16 + lr) * cC + quad * 8;
    bf16x8 na0 = *(const bf16x8*)np;
    bf16x8 na1 = *(const bf16x8*)(np + 32);
    int rb = mt * 16 + quad * 4;
#pragma unroll
    for (int tt = 0; tt < 8; tt++) {
      f32x4 acc = {0, 0, 0, 0};
      acc = mfma16(a0, bfr[tt][0], acc);
      acc = mfma16(a1, bfr[tt][1], acc);
      if (chunk_full) {
        cmax[tt] = fmaxf(cmax[tt], fmaxf(fmaxf(acc[0], acc[1]), fmaxf(acc[2], acc[3])));
      } else {
#pragma unroll
        for (int r = 0; r < 4; r++)
          cmax[tt] = fmaxf(cmax[tt], (rb + r) < P_valid ? acc[r] : -INFINITY);
      }
    }
    a0 = na0; a1 = na1;
  }
#pragma unroll
  for (int tt = 0; tt < 8; tt++) {
    float c = cmax[tt];
    c = fmaxf(c, __shfl_xor(c, 16));
    c = fmaxf(c, __shfl_xor(c, 32));
    cmax[tt] = c;
  }
  if (quad == 0) {
#pragma unroll
    for (int tt = 0; tt < 8; tt++) msout[colbase + tt * 16 + lr] = cmax[tt];
  }
}

// ---------------- top-KEEP selection (radix threshold; set semantics) ----------------
DEVI unsigned f2key(float f) {
  unsigned u = __float_as_uint(f);
  return (u & 0x80000000u) ? ~u : (u | 0x80000000u);
}

__device__ int scan_excl_1024(int v, int* lds, int* total) {
  int tid = threadIdx.x;
  lds[tid] = v;
  __syncthreads();
  for (int d = 1; d < 1024; d <<= 1) {
    int t = (tid >= d) ? lds[tid - d] : 0;
    __syncthreads();
    lds[tid] += t;
    __syncthreads();
  }
  *total = lds[1023];
  int e = lds[tid] - v;
  __syncthreads();
  return e;
}

__global__ __launch_bounds__(1024) void k_selneg(const float* msim, int* nsel, int* scal) {
  __shared__ int hist[256];
  __shared__ int suf[256];
  __shared__ int lds[1024];
  __shared__ unsigned sh_prefix;
  __shared__ int sh_rem;
  int b = blockIdx.x, tid = threadIdx.x;
  const float* ms0 = msim + ((size_t)b * 2 + 0) * cKC;
  const float* ms1 = msim + ((size_t)b * 2 + 1) * cKC;
  int P_valid = scal[b * 16 + 1], C_valid = scal[b * 16 + 2];
  int n_allowed = min(5 * P_valid, cKN);
  int nfin = (P_valid > 0) ? C_valid : 0;
  int KEEP = min(n_allowed, nfin);
  if (tid == 0) scal[b * 16 + 3] = KEEP;
  if (KEEP == 0) return;

  unsigned prefix = 0;
  int remaining = KEEP;
  for (int shift = 24; shift >= 0; shift -= 8) {
    if (tid < 256) hist[tid] = 0;
    __syncthreads();
    for (int c = tid; c < cKC; c += 1024) {
      unsigned key = (c < C_valid) ? f2key(fmaxf(ms0[c], ms1[c])) : 0u;
      if (shift == 24 || (key >> (shift + 8)) == prefix)
        atomicAdd(&hist[(key >> shift) & 255], 1);
    }
    __syncthreads();
    if (tid < 256) suf[tid] = hist[tid];
    __syncthreads();
    for (int d = 1; d < 256; d <<= 1) {
      int t = (tid < 256 && tid + d < 256) ? suf[tid + d] : 0;
      __syncthreads();
      if (tid < 256) suf[tid] += t;
      __syncthreads();
    }
    if (tid < 256) {
      int s = suf[tid];
      int sn = (tid < 255) ? suf[tid + 1] : 0;
      if (s >= remaining && sn < remaining) {
        sh_prefix = (prefix << 8) | (unsigned)tid;
        sh_rem = remaining - sn;
      }
    }
    __syncthreads();
    prefix = sh_prefix; remaining = sh_rem;
    __syncthreads();
  }
  unsigned T = prefix;

  const int CH2 = cKC / 1024;  // 20
  int s = tid * CH2;
  unsigned keys[CH2];
  int cntA = 0, cntT = 0;
  for (int e = 0; e < CH2; e++) {
    int c = s + e;
    unsigned key = (c < C_valid) ? f2key(fmaxf(ms0[c], ms1[c])) : 0u;
    keys[e] = key;
    cntA += (key > T);
    cntT += (key == T);
  }
  int totA, totT;
  int offA = scan_excl_1024(cntA, lds, &totA);
  int offT = scan_excl_1024(cntT, lds, &totT);
  int* out = nsel + (size_t)b * cKN;
  int oa = offA, ot = offT;
  for (int e = 0; e < CH2; e++) {
    unsigned key = keys[e];
    if (key > T) { out[oa++] = s + e; }
    else if (key == T) { if (ot < remaining) out[totA + ot] = s + e; ot++; }
  }
}

// ---------------- gather negatives into G (zero unused rows) ----------------
__global__ __launch_bounds__(256) void k_gather_neg(const __hip_bfloat16* cf, const int* nsel,
                                                    const int* scal, __hip_bfloat16* G) {
  int b = blockIdx.y;
  int KEEP = scal[b * 16 + 3];
  int t = blockIdx.x * 256 + threadIdx.x;
  int k = t >> 3, part = t & 7;
  if (k >= cKN) return;
  int4 val = {0, 0, 0, 0};
  if (k < KEEP) {
    int src = nsel[(size_t)b * cKN + k];
    val = *(const int4*)((const __bf16*)(cf + (size_t)b * cKC * cC) + (size_t)src * cC + part * 8);
  }
  *(int4*)((__bf16*)(G + (size_t)b * cNT * cC) + (size_t)(cP + k) * cC + part * 8) = val;
}

// ---------------- fused loss GEMM (64 rows/block, per-chunk partial E/L) ----------------
__global__ __launch_bounds__(256) void k_loss_part(const __hip_bfloat16* G, const int* scal, float2* ELp) {
  __shared__ float sE[4][64];
  __shared__ float sL[4][64];
  int b = blockIdx.z, chunk = blockIdx.y;
  int P_valid = scal[b * 16 + 1];
  int KEEP = scal[b * 16 + 3];
  if (P_valid < 2) return;   // image unused by finalize
  int wave = threadIdx.x >> 6, lane = threadIdx.x & 63;
  int lr = lane & 15, quad = lane >> 4;
  int rowbase = blockIdx.x * 64;
  const __bf16* Gb = (const __bf16*)G + (size_t)b * cNT * cC;

  bf16x8 afr[4][2];
#pragma unroll
  for (int rt = 0; rt < 4; rt++) {
    const __bf16* src = Gb + (size_t)(rowbase + rt * 16 + lr) * cC + quad * 8;
    afr[rt][0] = *(const bf16x8*)src;
    afr[rt][1] = *(const bf16x8*)(src + 32);
  }
  float eacc[4][4] = {};
  float lacc[4][4] = {};
  int ct0 = chunk * cTPC;
  for (int ct = ct0 + wave; ct < ct0 + cTPC; ct += 4) {
    int tb = ct * 16;
    bool is_pos = tb < cP;
    int vlimit = is_pos ? P_valid : (cP + KEEP);
    if (tb >= vlimit) continue;                       // wave-uniform skip
    bool all_valid = (tb + 16) <= vlimit;
    bool has_diag = is_pos && (tb >= rowbase) && (tb < rowbase + 64);
    const __bf16* bsrc = Gb + (size_t)(tb + lr) * cC + quad * 8;
    bf16x8 b0 = *(const bf16x8*)bsrc;
    bf16x8 b1 = *(const bf16x8*)(bsrc + 32);
    f32x4 acc[4];
#pragma unroll
    for (int rt = 0; rt < 4; rt++) {
      f32x4 a = {0, 0, 0, 0};
      a = mfma16(afr[rt][0], b0, a);
      a = mfma16(afr[rt][1], b1, a);
      acc[rt] = a;
    }
    if (all_valid && !has_diag) {
      if (is_pos) {
#pragma unroll
        for (int rt = 0; rt < 4; rt++)
#pragma unroll
          for (int r = 0; r < 4; r++) {
            float logit = acc[rt][r] * cTEMP_INV;
            eacc[rt][r] += __expf(logit);
            lacc[rt][r] += logit;
          }
      } else {
#pragma unroll
        for (int rt = 0; rt < 4; rt++)
#pragma unroll
          for (int r = 0; r < 4; r++)
            eacc[rt][r] += __expf(acc[rt][r] * cTEMP_INV);
      }
    } else {
      bool colv = (tb + lr) < vlimit;
#pragma unroll
      for (int rt = 0; rt < 4; rt++) {
        int rb = rowbase + rt * 16 + quad * 4;
#pragma unroll
        for (int r = 0; r < 4; r++) {
          float logit = acc[rt][r] * cTEMP_INV;
          bool use = colv && !(has_diag && (tb + lr) == (rb + r));
          float e = __expf(logit);
          eacc[rt][r] += use ? e : 0.0f;
          if (is_pos) lacc[rt][r] += use ? logit : 0.0f;
        }
      }
    }
  }
#pragma unroll
  for (int rt = 0; rt < 4; rt++) {
#pragma unroll
    for (int r = 0; r < 4; r++) {
      float e = eacc[rt][r], l = lacc[rt][r];
#pragma unroll
      for (int d = 1; d < 16; d <<= 1) {
        e += __shfl_xor(e, d);
        l += __shfl_xor(l, d);
      }
      if (lr == 0) {
        sE[wave][rt * 16 + quad * 4 + r] = e;
        sL[wave][rt * 16 + quad * 4 + r] = l;
      }
    }
  }
  __syncthreads();
  if (threadIdx.x < 64) {
    int row = rowbase + threadIdx.x;
    float E = sE[0][threadIdx.x] + sE[1][threadIdx.x] + sE[2][threadIdx.x] + sE[3][threadIdx.x];
    float L = sL[0][threadIdx.x] + sL[1][threadIdx.x] + sL[2][threadIdx.x] + sL[3][threadIdx.x];
    ELp[((size_t)chunk * cB + b) * cP + row] = make_float2(E, L);
  }
}

// ---------------- finalize: per-row loss, per-image mean, cross-image mean ----------------
__global__ __launch_bounds__(1024) void k_loss_fin(const int* scal, const float2* ELp, float* out) {
  __shared__ float ssum[16];
  int tid = threadIdx.x;
  int b = tid >> 8, t = tid & 255;
  int Pv = scal[b * 16 + 1];
  float s = 0.f;
  if (Pv >= 2) {
    float inv = 1.0f / (float)(Pv - 1);
#pragma unroll
    for (int e = 0; e < 8; e++) {
      int row = t * 8 + e;
      if (row < Pv) {
        float E = 0.f, L = 0.f;
#pragma unroll
        for (int ch = 0; ch < cNCH; ch++) {
          float2 el = ELp[((size_t)ch * cB + b) * cP + row];
          E += el.x; L += el.y;
        }
        s += logf(E) - L * inv;
      }
    }
  }
#pragma unroll
  for (int d = 1; d < 64; d <<= 1) s += __shfl_xor(s, d);
  if ((tid & 63) == 0) ssum[tid >> 6] = s;
  __syncthreads();
  if (tid == 0) {
    float tot = 0.f;
    int cnt = 0;
    for (int bb = 0; bb < cB; bb++) {
      int P = scal[bb * 16 + 1];
      if (P >= 2) {
        float is = ssum[bb * 4] + ssum[bb * 4 + 1] + ssum[bb * 4 + 2] + ssum[bb * 4 + 3];
        tot += is / (float)P;
        cnt++;
      }
    }
    out[0] = tot / (float)(cnt > 0 ? cnt : 1);
  }
}

extern "C" void kernel_launch(void* const* d_in, const int* in_sizes, int n_in,
                              void* d_out, int out_size, void* d_ws, size_t ws_size,
                              hipStream_t stream) {
  const float* feat = (const float*)d_in[0];
  const int* labels = (const int*)d_in[1];
  char* ws = (char*)d_ws;
  unsigned char* fg  = (unsigned char*)(ws + off_fg);
  unsigned char* tmp = (unsigned char*)(ws + off_tmp);
  unsigned char* rim = (unsigned char*)(ws + off_rim);
  int* pidx = (int*)(ws + off_pidx);
  int* cidx = (int*)(ws + off_cidx);
  int* scal = (int*)(ws + off_scal);
  float2* ELp = (float2*)(ws + off_EL);
  float* msim = (float*)(ws + off_msim);
  int* nsel = (int*)(ws + off_nsel);
  __hip_bfloat16* G  = (__hip_bfloat16*)(ws + off_G);
  __hip_bfloat16* cf = (__hip_bfloat16*)(ws + off_cf);
  int* blkcnt = (int*)(ws + off_bcnt);
  int2* blkoff = (int2*)(ws + off_boff);
  float* out = (float*)d_out;

  k_fg_hdil<<<cB * cHW / 8 / 256, 256, 0, stream>>>(labels, fg, tmp);
  k_vdil_count<<<dim3(cNB, cB), 256, 0, stream>>>(tmp, fg, rim, blkcnt);
  k_offsets<<<cB, 128, 0, stream>>>(blkcnt, blkoff, scal);
  k_scatter<<<dim3(cNB, cB), 256, 0, stream>>>(fg, rim, blkoff, scal, pidx, cidx);
  k_gather_norm<<<dim3(cP / 256 + cKC / 256, cB), 256, 0, stream>>>(feat, pidx, cidx, G, cf);
  k_mine<<<dim3(cKC / 512, 2, cB), 256, 0, stream>>>(G, cf, scal, msim);
  k_selneg<<<cB, 1024, 0, stream>>>(msim, nsel, scal);
  k_gather_neg<<<dim3(cKN * 8 / 256, cB), 256, 0, stream>>>(cf, nsel, scal, G);
  k_loss_part<<<dim3(cP / 64, cNCH, cB), 256, 0, stream>>>(G, scal, ELp);
  k_loss_fin<<<1, 1024, 0, stream>>>(scal, ELp, out);
}